// Round 13
// baseline (300.700 us; speedup 1.0000x reference)
//
#include <hip/hip_runtime.h>
#include <stdint.h>

#define S_LEN 512
#define I_DIM 28
#define H_DIM 128
#define O_DIM 28
#define BT    16   // batch rows per block; 8 waves, one 16-col tile per wave

typedef __attribute__((ext_vector_type(8))) short bf16x8;
typedef __attribute__((ext_vector_type(4))) float f32x4;

static __device__ __forceinline__ short f2bf(float f) {   // cold paths only
    unsigned u = __float_as_uint(f);
    u = (u + 0x7fffu + ((u >> 16) & 1u)) >> 16;
    return (short)u;
}
static __device__ __forceinline__ float bf2f(unsigned short u) {
    return __uint_as_float(((unsigned)u) << 16);
}
static __device__ __forceinline__ unsigned cvt_pk(float a, float b) {
    unsigned r;
    asm("v_cvt_pk_bf16_f32 %0, %1, %2" : "=v"(r) : "v"(a), "v"(b));
    return r;
}
// [5/4] Pade tanh on 4 values via packed-f32 (v_pk_*): ~18 pk + 4 trans.
// |err| <= ~1.1e-3 (< bf16 quant). Validated R10-R12.
static __device__ __forceinline__ f32x4 pade_tanh4(f32x4 x) {
    f32x4 u = x * x;
    f32x4 n = __builtin_elementwise_fma(u, u + 105.0f, (f32x4)(945.0f)) * x;
    f32x4 d = __builtin_elementwise_fma(
                  u, __builtin_elementwise_fma(u, (f32x4)(15.0f), (f32x4)(420.0f)),
                  (f32x4)(945.0f));
    f32x4 r;
    r[0] = __builtin_amdgcn_rcpf(d[0]); r[1] = __builtin_amdgcn_rcpf(d[1]);
    r[2] = __builtin_amdgcn_rcpf(d[2]); r[3] = __builtin_amdgcn_rcpf(d[3]);
    f32x4 t = n * r;
    t = __builtin_elementwise_max(t, (f32x4)(-1.0f));
    t = __builtin_elementwise_min(t, (f32x4)(1.0f));
    return t;
}

__global__ __launch_bounds__(512, 1) void rnn_fused(
    const float* __restrict__ x,
    const float* __restrict__ W_ih, const float* __restrict__ b_ih,
    const float* __restrict__ W_hh, const float* __restrict__ b_hh,
    const float* __restrict__ W_ho, const float* __restrict__ b_ho,
    float* __restrict__ out)
{
    const int tid  = threadIdx.x;
    const int wave = tid >> 6;         // 0..7 -> owns cols [16w, 16w+16)
    const int lane = tid & 63;
    const int l15  = lane & 15;        // batch-row slot
    const int lk   = lane >> 4;        // 0..3 k-group
    const int r0   = blockIdx.x * BT;

    // h^T B-fragments by 32-col chunk, double buffered. 8 KB total LDS.
    __shared__ __align__(16) bf16x8 hx[2][4][64];

    // ---- stationary A-fragments (swapped form, identity column map) ----
    // A[m=l15][k=8lk+e] = W_hh[k][16w+l15]; C reg r -> j = 16w + 4lk + r, b = l15.
    bf16x8 Ahh0, Ahh1, Ahh2, Ahh3, Aih;
    f32x4  biasv;
    const int jA = 16 * wave + l15;
    #pragma unroll
    for (int e = 0; e < 8; ++e) {
        Ahh0[e] = f2bf(W_hh[(  0 + lk * 8 + e) * H_DIM + jA]);
        Ahh1[e] = f2bf(W_hh[( 32 + lk * 8 + e) * H_DIM + jA]);
        Ahh2[e] = f2bf(W_hh[( 64 + lk * 8 + e) * H_DIM + jA]);
        Ahh3[e] = f2bf(W_hh[( 96 + lk * 8 + e) * H_DIM + jA]);
        int i = lk * 8 + e;
        Aih[e] = (i < I_DIM) ? f2bf(W_ih[i * H_DIM + jA]) : (short)0;
    }
    #pragma unroll
    for (int r = 0; r < 4; ++r) {
        int jC = 16 * wave + lk * 4 + r;
        biasv[r] = b_ih[jC] + b_hh[jC];
    }

    // ds_write target: produced (j=16w+4lk+r, b=l15) -> chunk w>>1,
    // lane' = (2(w&1)+(lk>>1))*16 + l15, byte 8*(lk&1)
    const int wboff = (wave >> 1) * 1024
                    + ((2 * (wave & 1) + (lk >> 1)) * 16 + l15) * 16
                    + 8 * (lk & 1);

    // h0 = 0 (hx[0] is 4 KB = 512 uint2)
    ((uint2*)&hx[0][0][0])[tid] = make_uint2(0u, 0u);

    // ---- x stays in registers: wave loads its OWN rows' frags directly ----
    // lane (lk,l15): lo = x[r0+l15][f][8lk..8lk+3], hi = [8lk+4..8lk+7].
    // lk==3: hi would be OOB; clamp to lo (Aih zeros kill the garbage: 0*finite=0).
    const float* xbase = x + (size_t)(r0 + l15) * S_LEN * I_DIM + lk * 8;
    const int hioff = (lk < 3) ? 4 : 0;   // floats

    float4 rl0, rl1, rl2, rl3, rl4, rl5, rl6, rl7;
    float4 rh0, rh1, rh2, rh3, rh4, rh5, rh6, rh7;
    bf16x8 xf0, xf1, xf2, xf3, xf4, xf5, xf6, xf7;

#define LOADG(T8)                                                              \
    {                                                                          \
        const float* g0 = xbase + (size_t)(T8) * I_DIM;                        \
        const float* g1 = g0 + hioff;                                          \
        rl0 = *(const float4*)(g0 + 0 * I_DIM); rh0 = *(const float4*)(g1 + 0 * I_DIM); \
        rl1 = *(const float4*)(g0 + 1 * I_DIM); rh1 = *(const float4*)(g1 + 1 * I_DIM); \
        rl2 = *(const float4*)(g0 + 2 * I_DIM); rh2 = *(const float4*)(g1 + 2 * I_DIM); \
        rl3 = *(const float4*)(g0 + 3 * I_DIM); rh3 = *(const float4*)(g1 + 3 * I_DIM); \
        rl4 = *(const float4*)(g0 + 4 * I_DIM); rh4 = *(const float4*)(g1 + 4 * I_DIM); \
        rl5 = *(const float4*)(g0 + 5 * I_DIM); rh5 = *(const float4*)(g1 + 5 * I_DIM); \
        rl6 = *(const float4*)(g0 + 6 * I_DIM); rh6 = *(const float4*)(g1 + 6 * I_DIM); \
        rl7 = *(const float4*)(g0 + 7 * I_DIM); rh7 = *(const float4*)(g1 + 7 * I_DIM); \
    }

#define CVT1(XF, RL, RH)                                                       \
    {                                                                          \
        union { bf16x8 v; unsigned u[4]; } fr_;                                \
        fr_.u[0] = cvt_pk(RL.x, RL.y); fr_.u[1] = cvt_pk(RL.z, RL.w);          \
        fr_.u[2] = cvt_pk(RH.x, RH.y); fr_.u[3] = cvt_pk(RH.z, RH.w);          \
        XF = fr_.v;                                                            \
    }

    // prolog: group 0 -> xf, group 1 -> raw
    LOADG(0)
    CVT1(xf0, rl0, rh0) CVT1(xf1, rl1, rh1) CVT1(xf2, rl2, rh2) CVT1(xf3, rl3, rh3)
    CVT1(xf4, rl4, rh4) CVT1(xf5, rl5, rh5) CVT1(xf6, rl6, rh6) CVT1(xf7, rl7, rh7)
    LOADG(8)

    // hoisted x-projection for step 0
    f32x4 xacc = biasv;
    xacc = __builtin_amdgcn_mfma_f32_16x16x32_bf16(Aih, xf0, xacc, 0, 0, 0);

    asm volatile("s_waitcnt lgkmcnt(0)" ::: "memory");
    __builtin_amdgcn_s_barrier();
    asm volatile("" ::: "memory");

// One step. PAR compile-time. Entering: xacc = bias + Aih.x_t.
// 4 chunk reads (loop-invariant addresses), 4-MFMA (2+2), next xacc under the
// packed-tanh window, one b64 write, drain write, barrier.
#define RSTEP(PAR, XN)                                                         \
    {                                                                          \
        const bf16x8* hxp = &hx[PAR][0][0];                                    \
        bf16x8 b0 = hxp[0 * 64 + lane];                                        \
        bf16x8 b1 = hxp[1 * 64 + lane];                                        \
        bf16x8 b2 = hxp[2 * 64 + lane];                                        \
        bf16x8 b3 = hxp[3 * 64 + lane];                                        \
        f32x4 a = xacc;                                                        \
        a = __builtin_amdgcn_mfma_f32_16x16x32_bf16(Ahh0, b0, a, 0, 0, 0);     \
        a = __builtin_amdgcn_mfma_f32_16x16x32_bf16(Ahh1, b1, a, 0, 0, 0);     \
        f32x4 c = {0.f, 0.f, 0.f, 0.f};                                        \
        c = __builtin_amdgcn_mfma_f32_16x16x32_bf16(Ahh2, b2, c, 0, 0, 0);     \
        c = __builtin_amdgcn_mfma_f32_16x16x32_bf16(Ahh3, b3, c, 0, 0, 0);     \
        f32x4 s = a + c;                                                       \
        /* next step's x-projection: MFMA pipe idle during tanh */             \
        xacc = biasv;                                                          \
        xacc = __builtin_amdgcn_mfma_f32_16x16x32_bf16(Aih, XN, xacc, 0, 0, 0);\
        f32x4 h = pade_tanh4(s);                                               \
        uint2 wv;                                                              \
        wv.x = cvt_pk(h[0], h[1]); wv.y = cvt_pk(h[2], h[3]);                  \
        *(uint2*)((char*)&hx[(PAR) ^ 1][0][0] + wboff) = wv;                   \
        asm volatile("s_waitcnt lgkmcnt(0)" ::: "memory");                     \
        __builtin_amdgcn_s_barrier();                                          \
        asm volatile("" ::: "memory");                                        \
    }

    for (int t8 = 0; t8 < S_LEN; t8 += 8) {
        // invariant at group top: xf = group t8, raw = group t8+8 (in flight/arrived)
        RSTEP(0, xf1)
        RSTEP(1, xf2)
        RSTEP(0, xf3)
        RSTEP(1, xf4)
        RSTEP(0, xf5)
        RSTEP(1, xf6)
        RSTEP(0, xf7)
        // frame 0 of NEXT group (raw loaded >=1 group ago -> arrived)
        bf16x8 xf0n;
        CVT1(xf0n, rl0, rh0)
        RSTEP(1, xf0n)
        if (t8 + 8 < S_LEN) {                       // prep next group
            xf0 = xf0n;
            CVT1(xf1, rl1, rh1) CVT1(xf2, rl2, rh2) CVT1(xf3, rl3, rh3)
            CVT1(xf4, rl4, rh4) CVT1(xf5, rl5, rh5) CVT1(xf6, rl6, rh6)
            CVT1(xf7, rl7, rh7)
            if (t8 + 16 < S_LEN) LOADG(t8 + 16)     // issue group t8+16
        }
    }
#undef RSTEP
#undef CVT1
#undef LOADG

    // ---- epilogue: out = h_512 @ W_ho + b_ho ; final h in hx[0] ----
    // h[b][j]: chunk j>>5, lane ((j>>3)&3)*16 + b, halfword j&7
    for (int idx = tid; idx < BT * O_DIM; idx += 512) {
        const int b = idx / O_DIM;
        const int o = idx - b * O_DIM;
        float sum = b_ho[o];
        const unsigned short* hb = (const unsigned short*)&hx[0][0][0];
        #pragma unroll 4
        for (int j = 0; j < H_DIM; ++j) {
            int slot = (j >> 5) * 64 + ((j >> 3) & 3) * 16 + b;
            sum += bf2f(hb[slot * 8 + (j & 7)]) * W_ho[j * O_DIM + o];
        }
        out[(size_t)(r0 + b) * O_DIM + o] = sum;
    }
}

extern "C" void kernel_launch(void* const* d_in, const int* in_sizes, int n_in,
                              void* d_out, int out_size, void* d_ws, size_t ws_size,
                              hipStream_t stream) {
    const float* x    = (const float*)d_in[0];
    const float* W_ih = (const float*)d_in[1];
    const float* b_ih = (const float*)d_in[2];
    const float* W_hh = (const float*)d_in[3];
    const float* b_hh = (const float*)d_in[4];
    const float* W_ho = (const float*)d_in[5];
    const float* b_ho = (const float*)d_in[6];
    const int B = in_sizes[0] / (S_LEN * I_DIM);   // 4096
    rnn_fused<<<B / BT, 512, 0, stream>>>(x, W_ih, b_ih, W_hh, b_hh, W_ho, b_ho,
                                          (float*)d_out);
}

// Round 14
// 168.824 us; speedup vs baseline: 1.7811x; 1.7811x over previous
//
#include <hip/hip_runtime.h>
#include <stdint.h>

#define S_LEN 512
#define I_DIM 28
#define H_DIM 128
#define O_DIM 28
#define BT    16   // batch rows per block; 8 waves, one 16-col tile per wave

typedef __attribute__((ext_vector_type(8))) short bf16x8;
typedef __attribute__((ext_vector_type(4))) float f32x4;

static __device__ __forceinline__ short f2bf(float f) {   // cold paths only
    unsigned u = __float_as_uint(f);
    u = (u + 0x7fffu + ((u >> 16) & 1u)) >> 16;
    return (short)u;
}
static __device__ __forceinline__ float bf2f(unsigned short u) {
    return __uint_as_float(((unsigned)u) << 16);
}
static __device__ __forceinline__ unsigned cvt_pk(float a, float b) {
    unsigned r;
    asm("v_cvt_pk_bf16_f32 %0, %1, %2" : "=v"(r) : "v"(a), "v"(b));
    return r;
}
// [5/4] Pade tanh on 4 values, packed-f32 VALU + ONE rcp via the
// reciprocal-product identity: rP=rcp(d0 d1 d2 d3); 1/di = rP * prod(dj!=i).
// |approx err| <= ~1.1e-3 (< bf16 quant); extra rounding ~5e-7. R10-R12 math.
static __device__ __forceinline__ f32x4 pade_tanh4(f32x4 x) {
    f32x4 u = x * x;
    f32x4 n = __builtin_elementwise_fma(u, u + 105.0f, (f32x4)(945.0f)) * x;
    f32x4 d = __builtin_elementwise_fma(
                  u, __builtin_elementwise_fma(u, (f32x4)(15.0f), (f32x4)(420.0f)),
                  (f32x4)(945.0f));
    float p01 = d[0] * d[1], p23 = d[2] * d[3];
    float rP  = __builtin_amdgcn_rcpf(p01 * p23);
    float r01 = rP * p23, r23 = rP * p01;
    f32x4 r;
    r[0] = r01 * d[1]; r[1] = r01 * d[0];
    r[2] = r23 * d[3]; r[3] = r23 * d[2];
    f32x4 t = n * r;
    t = __builtin_elementwise_max(t, (f32x4)(-1.0f));
    t = __builtin_elementwise_min(t, (f32x4)(1.0f));
    return t;
}

__global__ __launch_bounds__(512, 1) void rnn_fused(
    const float* __restrict__ x,
    const float* __restrict__ W_ih, const float* __restrict__ b_ih,
    const float* __restrict__ W_hh, const float* __restrict__ b_hh,
    const float* __restrict__ W_ho, const float* __restrict__ b_ho,
    float* __restrict__ out)
{
    const int tid  = threadIdx.x;
    const int wave = tid >> 6;         // 0..7 -> owns cols [16w, 16w+16)
    const int lane = tid & 63;
    const int l15  = lane & 15;        // batch-row slot
    const int lk   = lane >> 4;        // 0..3 k-group
    const int r0   = blockIdx.x * BT;

    // h^T B-fragments by 32-col chunk, double buffered (8 KB); x ring (16 KB)
    __shared__ __align__(16) bf16x8 hx[2][4][64];
    __shared__ __align__(16) bf16x8 xring[16][64];

    // ---- stationary A-fragments (swapped form, identity column map) ----
    // A[m=l15][k=8lk+e] = W_hh[k][16w+l15]; C reg r -> j = 16w + 4lk + r, b = l15.
    bf16x8 Ahh0, Ahh1, Ahh2, Ahh3, Aih;
    f32x4  biasv;
    const int jA = 16 * wave + l15;
    #pragma unroll
    for (int e = 0; e < 8; ++e) {
        Ahh0[e] = f2bf(W_hh[(  0 + lk * 8 + e) * H_DIM + jA]);
        Ahh1[e] = f2bf(W_hh[( 32 + lk * 8 + e) * H_DIM + jA]);
        Ahh2[e] = f2bf(W_hh[( 64 + lk * 8 + e) * H_DIM + jA]);
        Ahh3[e] = f2bf(W_hh[( 96 + lk * 8 + e) * H_DIM + jA]);
        int i = lk * 8 + e;
        Aih[e] = (i < I_DIM) ? f2bf(W_ih[i * H_DIM + jA]) : (short)0;
    }
    #pragma unroll
    for (int r = 0; r < 4; ++r) {
        int jC = 16 * wave + lk * 4 + r;
        biasv[r] = b_ih[jC] + b_hh[jC];
    }

    // ds_write target: produced (j=16w+4lk+r, b=l15) -> chunk w>>1,
    // lane' = (2(w&1)+(lk>>1))*16 + l15, byte 8*(lk&1)
    const int wboff = (wave >> 1) * 1024
                    + ((2 * (wave & 1) + (lk >> 1)) * 16 + l15) * 16
                    + 8 * (lk & 1);

    // h0 = 0
    ((uint2*)&hx[0][0][0])[tid] = make_uint2(0u, 0u);

    const bool hasHi = (lk < 3);       // k-group 3: only i=24..27 valid
    const float* xbase = x + (size_t)(r0 + l15) * S_LEN * I_DIM + lk * 8;

    // ---- prologue: wave w stages x frame w (frames 0..7) ----
    {
        const float* src = xbase + wave * I_DIM;
        float4 lo = *(const float4*)src;
        float4 hi = hasHi ? *(const float4*)(src + 4) : make_float4(0.f,0.f,0.f,0.f);
        union { bf16x8 v; unsigned u[4]; } fr;
        fr.u[0] = cvt_pk(lo.x, lo.y); fr.u[1] = cvt_pk(lo.z, lo.w);
        fr.u[2] = cvt_pk(hi.x, hi.y); fr.u[3] = cvt_pk(hi.z, hi.w);
        xring[wave][lane] = fr.v;
    }
    asm volatile("s_waitcnt lgkmcnt(0)" ::: "memory");
    __builtin_amdgcn_s_barrier();
    asm volatile("" ::: "memory");

    // hoisted x-projection accumulator for the upcoming step:
    // xacc = bias + Aih . x_t  (always computed one step ahead, off the path)
    f32x4 xacc;
    {
        bf16x8 x0 = xring[0][lane];
        xacc = biasv;
        xacc = __builtin_amdgcn_mfma_f32_16x16x32_bf16(Aih, x0, xacc, 0, 0, 0);
    }

// One step. PAR/P compile-time literals. Entering: xacc = bias + Aih.x_t.
// Reads 4 h-chunks + next x-frag (latency-batched), 4-MFMA (2+2 split),
// computes next xacc under the packed tanh window, b64 write, drain, barrier.
#define RSTEP(PAR, P)                                                          \
    {                                                                          \
        const bf16x8* hxp = &hx[PAR][0][0];                                    \
        bf16x8 b0 = hxp[0 * 64 + lane];                                        \
        bf16x8 b1 = hxp[1 * 64 + lane];                                        \
        bf16x8 b2 = hxp[2 * 64 + lane];                                        \
        bf16x8 b3 = hxp[3 * 64 + lane];                                        \
        bf16x8 xn = xring[(t8 + P + 1) & 15][lane]; /* slot written >=1 barrier ago */ \
        if (P == 0 && doPf) {                                                  \
            const float* src = xbase + (size_t)tf * I_DIM;                     \
            pf_lo = *(const float4*)src;                                       \
            if (hasHi) pf_hi = *(const float4*)(src + 4);                      \
        }                                                                      \
        f32x4 a = xacc;                                                        \
        a = __builtin_amdgcn_mfma_f32_16x16x32_bf16(Ahh0, b0, a, 0, 0, 0);     \
        a = __builtin_amdgcn_mfma_f32_16x16x32_bf16(Ahh1, b1, a, 0, 0, 0);     \
        f32x4 c = {0.f, 0.f, 0.f, 0.f};                                        \
        c = __builtin_amdgcn_mfma_f32_16x16x32_bf16(Ahh2, b2, c, 0, 0, 0);     \
        c = __builtin_amdgcn_mfma_f32_16x16x32_bf16(Ahh3, b3, c, 0, 0, 0);     \
        if (P == 2 && doPf) {                                                  \
            union { bf16x8 v; unsigned u[4]; } fr;                             \
            fr.u[0] = cvt_pk(pf_lo.x, pf_lo.y); fr.u[1] = cvt_pk(pf_lo.z, pf_lo.w); \
            fr.u[2] = cvt_pk(pf_hi.x, pf_hi.y); fr.u[3] = cvt_pk(pf_hi.z, pf_hi.w); \
            xring[tf & 15][lane] = fr.v;                                       \
        }                                                                      \
        f32x4 s = a + c;                                                       \
        /* next step's x-projection: MFMA pipe is idle during tanh */          \
        xacc = biasv;                                                          \
        xacc = __builtin_amdgcn_mfma_f32_16x16x32_bf16(Aih, xn, xacc, 0, 0, 0);\
        f32x4 h = pade_tanh4(s);                                               \
        uint2 wv;                                                              \
        wv.x = cvt_pk(h[0], h[1]); wv.y = cvt_pk(h[2], h[3]);                  \
        *(uint2*)((char*)&hx[(PAR) ^ 1][0][0] + wboff) = wv;                   \
        asm volatile("s_waitcnt lgkmcnt(0)" ::: "memory");                     \
        __builtin_amdgcn_s_barrier();                                          \
        asm volatile("" ::: "memory");                                        \
    }

    for (int t8 = 0; t8 < S_LEN; t8 += 8) {
        const int tf   = t8 + 8 + wave;            // x frame this wave stages
        const bool doPf = (tf < S_LEN);
        float4 pf_lo = make_float4(0.f,0.f,0.f,0.f), pf_hi = pf_lo;
        RSTEP(0, 0)
        RSTEP(1, 1)
        RSTEP(0, 2)
        RSTEP(1, 3)
        RSTEP(0, 4)
        RSTEP(1, 5)
        RSTEP(0, 6)
        RSTEP(1, 7)
    }
#undef RSTEP

    // ---- epilogue: out = h_512 @ W_ho + b_ho ; final h in hx[0] ----
    // h[b][j]: chunk j>>5, lane ((j>>3)&3)*16 + b, halfword j&7
    for (int idx = tid; idx < BT * O_DIM; idx += 512) {
        const int b = idx / O_DIM;
        const int o = idx - b * O_DIM;
        float sum = b_ho[o];
        const unsigned short* hb = (const unsigned short*)&hx[0][0][0];
        #pragma unroll 4
        for (int j = 0; j < H_DIM; ++j) {
            int slot = (j >> 5) * 64 + ((j >> 3) & 3) * 16 + b;
            sum += bf2f(hb[slot * 8 + (j & 7)]) * W_ho[j * O_DIM + o];
        }
        out[(size_t)(r0 + b) * O_DIM + o] = sum;
    }
}

extern "C" void kernel_launch(void* const* d_in, const int* in_sizes, int n_in,
                              void* d_out, int out_size, void* d_ws, size_t ws_size,
                              hipStream_t stream) {
    const float* x    = (const float*)d_in[0];
    const float* W_ih = (const float*)d_in[1];
    const float* b_ih = (const float*)d_in[2];
    const float* W_hh = (const float*)d_in[3];
    const float* b_hh = (const float*)d_in[4];
    const float* W_ho = (const float*)d_in[5];
    const float* b_ho = (const float*)d_in[6];
    const int B = in_sizes[0] / (S_LEN * I_DIM);   // 4096
    rnn_fused<<<B / BT, 512, 0, stream>>>(x, W_ih, b_ih, W_hh, b_hh, W_ho, b_ho,
                                          (float*)d_out);
}

// Round 15
// 161.659 us; speedup vs baseline: 1.8601x; 1.0443x over previous
//
#include <hip/hip_runtime.h>
#include <stdint.h>

#define S_LEN 512
#define I_DIM 28
#define H_DIM 128
#define O_DIM 28
#define BT    16   // batch rows per block; 8 waves, one 16-col tile per wave

typedef __attribute__((ext_vector_type(8))) short bf16x8;
typedef __attribute__((ext_vector_type(4))) float f32x4;

static __device__ __forceinline__ short f2bf(float f) {   // cold paths only
    unsigned u = __float_as_uint(f);
    u = (u + 0x7fffu + ((u >> 16) & 1u)) >> 16;
    return (short)u;
}
static __device__ __forceinline__ float bf2f(unsigned short u) {
    return __uint_as_float(((unsigned)u) << 16);
}
static __device__ __forceinline__ unsigned cvt_pk(float a, float b) {
    unsigned r;
    asm("v_cvt_pk_bf16_f32 %0, %1, %2" : "=v"(r) : "v"(a), "v"(b));
    return r;
}
// [5/4] Pade tanh on 4 values via packed-f32 (v_pk_*): ~18 pk + 4 independent
// rcps (pipelined). |err| <= ~1.1e-3 (< bf16 quant). R12-verified best form:
// R14 proved the 1-rcp product identity LOSES (serial chain > trans savings).
static __device__ __forceinline__ f32x4 pade_tanh4(f32x4 x) {
    f32x4 u = x * x;
    f32x4 n = __builtin_elementwise_fma(u, u + 105.0f, (f32x4)(945.0f)) * x;
    f32x4 d = __builtin_elementwise_fma(
                  u, __builtin_elementwise_fma(u, (f32x4)(15.0f), (f32x4)(420.0f)),
                  (f32x4)(945.0f));
    f32x4 r;
    r[0] = __builtin_amdgcn_rcpf(d[0]); r[1] = __builtin_amdgcn_rcpf(d[1]);
    r[2] = __builtin_amdgcn_rcpf(d[2]); r[3] = __builtin_amdgcn_rcpf(d[3]);
    f32x4 t = n * r;
    t = __builtin_elementwise_max(t, (f32x4)(-1.0f));
    t = __builtin_elementwise_min(t, (f32x4)(1.0f));
    return t;
}

__global__ __launch_bounds__(512, 1) void rnn_fused(
    const float* __restrict__ x,
    const float* __restrict__ W_ih, const float* __restrict__ b_ih,
    const float* __restrict__ W_hh, const float* __restrict__ b_hh,
    const float* __restrict__ W_ho, const float* __restrict__ b_ho,
    float* __restrict__ out)
{
    const int tid  = threadIdx.x;
    const int wave = tid >> 6;         // 0..7 -> owns cols [16w, 16w+16)
    const int lane = tid & 63;
    const int l15  = lane & 15;        // batch-row slot
    const int lk   = lane >> 4;        // 0..3 k-group
    const int r0   = blockIdx.x * BT;

    // h^T B-fragments by 32-col chunk, double buffered (8 KB); x ring (16 KB)
    __shared__ __align__(16) bf16x8 hx[2][4][64];
    __shared__ __align__(16) bf16x8 xring[16][64];

    // ---- stationary A-fragments (swapped form, identity column map) ----
    // A[m=l15][k=8lk+e] = W_hh[k][16w+l15]; C reg r -> j = 16w + 4lk + r, b = l15.
    bf16x8 Ahh0, Ahh1, Ahh2, Ahh3, Aih;
    f32x4  biasv;
    const int jA = 16 * wave + l15;
    #pragma unroll
    for (int e = 0; e < 8; ++e) {
        Ahh0[e] = f2bf(W_hh[(  0 + lk * 8 + e) * H_DIM + jA]);
        Ahh1[e] = f2bf(W_hh[( 32 + lk * 8 + e) * H_DIM + jA]);
        Ahh2[e] = f2bf(W_hh[( 64 + lk * 8 + e) * H_DIM + jA]);
        Ahh3[e] = f2bf(W_hh[( 96 + lk * 8 + e) * H_DIM + jA]);
        int i = lk * 8 + e;
        Aih[e] = (i < I_DIM) ? f2bf(W_ih[i * H_DIM + jA]) : (short)0;
    }
    #pragma unroll
    for (int r = 0; r < 4; ++r) {
        int jC = 16 * wave + lk * 4 + r;
        biasv[r] = b_ih[jC] + b_hh[jC];
    }

    // ds_write target: produced (j=16w+4lk+r, b=l15) -> chunk w>>1,
    // lane' = (2(w&1)+(lk>>1))*16 + l15, byte 8*(lk&1)
    const int wboff = (wave >> 1) * 1024
                    + ((2 * (wave & 1) + (lk >> 1)) * 16 + l15) * 16
                    + 8 * (lk & 1);

    // h0 = 0
    ((uint2*)&hx[0][0][0])[tid] = make_uint2(0u, 0u);

    const bool hasHi = (lk < 3);       // k-group 3: only i=24..27 valid
    const float* xbase = x + (size_t)(r0 + l15) * S_LEN * I_DIM + lk * 8;

    // ---- prologue: wave w stages x frame w (frames 0..7) ----
    {
        const float* src = xbase + wave * I_DIM;
        float4 lo = *(const float4*)src;
        float4 hi = hasHi ? *(const float4*)(src + 4) : make_float4(0.f,0.f,0.f,0.f);
        union { bf16x8 v; unsigned u[4]; } fr;
        fr.u[0] = cvt_pk(lo.x, lo.y); fr.u[1] = cvt_pk(lo.z, lo.w);
        fr.u[2] = cvt_pk(hi.x, hi.y); fr.u[3] = cvt_pk(hi.z, hi.w);
        xring[wave][lane] = fr.v;
    }
    asm volatile("s_waitcnt lgkmcnt(0)" ::: "memory");
    __builtin_amdgcn_s_barrier();
    asm volatile("" ::: "memory");

    // hoisted x-projection accumulator for the upcoming step:
    // xacc = bias + Aih . x_t  (always computed one step ahead, off the path)
    f32x4 xacc;
    {
        bf16x8 x0 = xring[0][lane];
        xacc = biasv;
        xacc = __builtin_amdgcn_mfma_f32_16x16x32_bf16(Aih, x0, xacc, 0, 0, 0);
    }

// One step. PAR/P compile-time literals. Entering: xacc = bias + Aih.x_t.
// Reads 4 h-chunks + next x-frag (latency-batched), 4-MFMA (2+2 split),
// computes next xacc under the packed tanh window, b64 write, drain, barrier.
#define RSTEP(PAR, P)                                                          \
    {                                                                          \
        const bf16x8* hxp = &hx[PAR][0][0];                                    \
        bf16x8 b0 = hxp[0 * 64 + lane];                                        \
        bf16x8 b1 = hxp[1 * 64 + lane];                                        \
        bf16x8 b2 = hxp[2 * 64 + lane];                                        \
        bf16x8 b3 = hxp[3 * 64 + lane];                                        \
        bf16x8 xn = xring[(t8 + P + 1) & 15][lane]; /* slot written >=1 barrier ago */ \
        if (P == 0 && doPf) {                                                  \
            const float* src = xbase + (size_t)tf * I_DIM;                     \
            pf_lo = *(const float4*)src;                                       \
            if (hasHi) pf_hi = *(const float4*)(src + 4);                      \
        }                                                                      \
        f32x4 a = xacc;                                                        \
        a = __builtin_amdgcn_mfma_f32_16x16x32_bf16(Ahh0, b0, a, 0, 0, 0);     \
        a = __builtin_amdgcn_mfma_f32_16x16x32_bf16(Ahh1, b1, a, 0, 0, 0);     \
        f32x4 c = {0.f, 0.f, 0.f, 0.f};                                        \
        c = __builtin_amdgcn_mfma_f32_16x16x32_bf16(Ahh2, b2, c, 0, 0, 0);     \
        c = __builtin_amdgcn_mfma_f32_16x16x32_bf16(Ahh3, b3, c, 0, 0, 0);     \
        if (P == 2 && doPf) {                                                  \
            union { bf16x8 v; unsigned u[4]; } fr;                             \
            fr.u[0] = cvt_pk(pf_lo.x, pf_lo.y); fr.u[1] = cvt_pk(pf_lo.z, pf_lo.w); \
            fr.u[2] = cvt_pk(pf_hi.x, pf_hi.y); fr.u[3] = cvt_pk(pf_hi.z, pf_hi.w); \
            xring[tf & 15][lane] = fr.v;                                       \
        }                                                                      \
        f32x4 s = a + c;                                                       \
        /* next step's x-projection: MFMA pipe is idle during tanh */          \
        xacc = biasv;                                                          \
        xacc = __builtin_amdgcn_mfma_f32_16x16x32_bf16(Aih, xn, xacc, 0, 0, 0);\
        f32x4 h = pade_tanh4(s);                                               \
        uint2 wv;                                                              \
        wv.x = cvt_pk(h[0], h[1]); wv.y = cvt_pk(h[2], h[3]);                  \
        *(uint2*)((char*)&hx[(PAR) ^ 1][0][0] + wboff) = wv;                   \
        asm volatile("s_waitcnt lgkmcnt(0)" ::: "memory");                     \
        __builtin_amdgcn_s_barrier();                                          \
        asm volatile("" ::: "memory");                                        \
    }

    for (int t8 = 0; t8 < S_LEN; t8 += 8) {
        const int tf   = t8 + 8 + wave;            // x frame this wave stages
        const bool doPf = (tf < S_LEN);
        float4 pf_lo = make_float4(0.f,0.f,0.f,0.f), pf_hi = pf_lo;
        RSTEP(0, 0)
        RSTEP(1, 1)
        RSTEP(0, 2)
        RSTEP(1, 3)
        RSTEP(0, 4)
        RSTEP(1, 5)
        RSTEP(0, 6)
        RSTEP(1, 7)
    }
#undef RSTEP

    // ---- epilogue: out = h_512 @ W_ho + b_ho ; final h in hx[0] ----
    // h[b][j]: chunk j>>5, lane ((j>>3)&3)*16 + b, halfword j&7
    for (int idx = tid; idx < BT * O_DIM; idx += 512) {
        const int b = idx / O_DIM;
        const int o = idx - b * O_DIM;
        float sum = b_ho[o];
        const unsigned short* hb = (const unsigned short*)&hx[0][0][0];
        #pragma unroll 4
        for (int j = 0; j < H_DIM; ++j) {
            int slot = (j >> 5) * 64 + ((j >> 3) & 3) * 16 + b;
            sum += bf2f(hb[slot * 8 + (j & 7)]) * W_ho[j * O_DIM + o];
        }
        out[(size_t)(r0 + b) * O_DIM + o] = sum;
    }
}

extern "C" void kernel_launch(void* const* d_in, const int* in_sizes, int n_in,
                              void* d_out, int out_size, void* d_ws, size_t ws_size,
                              hipStream_t stream) {
    const float* x    = (const float*)d_in[0];
    const float* W_ih = (const float*)d_in[1];
    const float* b_ih = (const float*)d_in[2];
    const float* W_hh = (const float*)d_in[3];
    const float* b_hh = (const float*)d_in[4];
    const float* W_ho = (const float*)d_in[5];
    const float* b_ho = (const float*)d_in[6];
    const int B = in_sizes[0] / (S_LEN * I_DIM);   // 4096
    rnn_fused<<<B / BT, 512, 0, stream>>>(x, W_ih, b_ih, W_hh, b_hh, W_ho, b_ho,
                                          (float*)d_out);
}